// Round 5
// baseline (306.004 us; speedup 1.0000x reference)
//
#include <hip/hip_runtime.h>

// ---------------------------------------------------------------------------
// Fused: qkv-proj + head-LN (fused epilogue) -> cross-attention (x2) -> proj
// B=4, N=1024, C=768, H=12, HD=64.  All MFMA bf16 16x16x32, f32 accum.
//
// GEMM: BARRIER-FREE.  One wave = one 64x64 C-tile; A/B fragments loaded
// directly global->VGPR in MFMA A-layout (NT gemm: identical pattern for B).
// No LDS, no s_barrier -> waves never lockstep, latency hidden by TLP
// (gemm0: 4608 independent waves) + 3-stage register pipeline (16 loads in
// flight/wave).  Rounds 2-4 showed any barrier-coupled K-loop pays full
// queue-inflated memory latency per iteration at this short K (12 iters).
//
// ws layout (ushort elements):
//   xb     @ 0         : [8192 x 768]  before rows 0..4095, after 4096..8191
//   (vtg   @ 0         : [96 x 64 x 1024]  V^T per head -- reuses xb)
//   wqkvb  @ 6291456   : [2304 x 768]
//   wprojb @ 8060928   : [768 x 768]
//   qkvr   @ 8650752   : [8192 x 2304]  post-LN qkv
//   ctx    @ 27525120  : [8192 x 768]
// ---------------------------------------------------------------------------

typedef __bf16 bf16x8 __attribute__((ext_vector_type(8)));
typedef float  f32x4  __attribute__((ext_vector_type(4)));
typedef unsigned int u32x4 __attribute__((ext_vector_type(4)));

#define MFMA16(a, b, c) __builtin_amdgcn_mfma_f32_16x16x32_bf16(a, b, c, 0, 0, 0)

__device__ __forceinline__ unsigned short f2bf(float f) {
  unsigned int u = __builtin_bit_cast(unsigned int, f);
  u += 0x7FFFu + ((u >> 16) & 1u);   // RNE
  return (unsigned short)(u >> 16);
}
__device__ __forceinline__ float bf2f(unsigned short h) {
  unsigned int u = ((unsigned int)h) << 16;
  return __builtin_bit_cast(float, u);
}
__device__ __forceinline__ bf16x8 ld16(const unsigned short* p) {
  return __builtin_bit_cast(bf16x8, *(const u32x4*)p);
}
// Raw barrier: orders LDS only; does NOT drain in-flight global loads.
__device__ __forceinline__ void barrier_lds() {
  asm volatile("s_waitcnt lgkmcnt(0)\n\ts_barrier" ::: "memory");
}

// ---------------------------------------------------------------- convert --
__global__ __launch_bounds__(256) void k_convert(
    const float* __restrict__ before, const float* __restrict__ after,
    const float* __restrict__ wqkv, const float* __restrict__ wproj,
    unsigned short* __restrict__ ws) {
  int t = blockIdx.x * 256 + threadIdx.x;   // one float4 per thread
  const float* src; unsigned short* dst; int idx;
  if (t < 786432)       { src = before; dst = ws;           idx = t; }
  else if (t < 1572864) { src = after;  dst = ws + 3145728; idx = t - 786432; }
  else if (t < 2015232) { src = wqkv;   dst = ws + 6291456; idx = t - 1572864; }
  else                  { src = wproj;  dst = ws + 8060928; idx = t - 2015232; }
  float4 v = ((const float4*)src)[idx];
  ushort4 o;
  o.x = f2bf(v.x); o.y = f2bf(v.y); o.z = f2bf(v.z); o.w = f2bf(v.w);
  ((ushort4*)dst)[idx] = o;
}

// ------------------------------------------------------------------- GEMM --
// NT GEMM: C[m,n] = dot(A[m,:], B[n,:]).  Wave tile 64x64 (4x4 frags).
// Block = 4 independent waves, same m-tile, 4 consecutive n-tiles (the 4
// waves read identical A bytes -> L1 dedup).  K-steps of 32, 3-stage reg
// rotation (prefetch distance 2).  No LDS, no barriers.
// MODE 0: per-head LayerNorm fused epilogue, bf16 out (qkv).
// MODE 1: f32 out + bias + untransposed-q residual (final proj).
template <int K, int MODE>
__global__ __launch_bounds__(256) void k_gemm(
    const unsigned short* __restrict__ A, const unsigned short* __restrict__ B,
    void* __restrict__ Cout, const unsigned short* __restrict__ qkvr,
    const float* __restrict__ bias, const float* __restrict__ g,
    const float* __restrict__ bb, int ldc) {
  constexpr int NS = K / 32;                // K-steps
  const int lane = threadIdx.x & 63, w = threadIdx.x >> 6;
  const int quad = lane >> 4, l15 = lane & 15;
  const int m0 = blockIdx.y * 64;
  const int n0 = (blockIdx.x * 4 + w) * 64;
  const unsigned short* Ap = A + (size_t)(m0 + l15) * K + quad * 8;
  const unsigned short* Bp = B + (size_t)(n0 + l15) * K + quad * 8;
  f32x4 acc[4][4] = {};
  bf16x8 af[3][4], bfv[3][4];               // 3 pipeline stages

  auto loadf = [&](int s, int k0) {
#pragma unroll
    for (int f = 0; f < 4; ++f) {
      af[s][f]  = ld16(Ap + (size_t)f * 16 * K + k0);
      bfv[s][f] = ld16(Bp + (size_t)f * 16 * K + k0);
    }
  };

  loadf(0, 0);
  loadf(1, 32);
#pragma unroll
  for (int it = 0; it < NS; ++it) {
    const int p = it % 3;
    if (it + 2 < NS) loadf((it + 2) % 3, (it + 2) * 32);
#pragma unroll
    for (int mf = 0; mf < 4; ++mf)
#pragma unroll
      for (int nf = 0; nf < 4; ++nf)
        acc[mf][nf] = MFMA16(af[p][mf], bfv[p][nf], acc[mf][nf]);
  }

  if (MODE == 0) {
    // fused per-head LayerNorm: wave's 64 cols = exactly one (s,h) group
    unsigned short* C = (unsigned short*)Cout;
    float gl[4], bl[4];
#pragma unroll
    for (int nf = 0; nf < 4; ++nf) { gl[nf] = g[nf * 16 + l15]; bl[nf] = bb[nf * 16 + l15]; }
#pragma unroll
    for (int mf = 0; mf < 4; ++mf)
#pragma unroll
      for (int r = 0; r < 4; ++r) {
        float s1 = acc[mf][0][r] + acc[mf][1][r] + acc[mf][2][r] + acc[mf][3][r];
        float s2 = acc[mf][0][r] * acc[mf][0][r] + acc[mf][1][r] * acc[mf][1][r]
                 + acc[mf][2][r] * acc[mf][2][r] + acc[mf][3][r] * acc[mf][3][r];
#pragma unroll
        for (int o = 1; o < 16; o <<= 1) { s1 += __shfl_xor(s1, o); s2 += __shfl_xor(s2, o); }
        float mu = s1 * (1.0f / 64.0f);
        float var = s2 * (1.0f / 64.0f) - mu * mu;
        float sc = rsqrtf(var + 1e-5f);
        int row = m0 + mf * 16 + quad * 4 + r;
        size_t base = (size_t)row * ldc + n0 + l15;
#pragma unroll
        for (int nf = 0; nf < 4; ++nf)
          C[base + nf * 16] = f2bf((acc[mf][nf][r] - mu) * sc * gl[nf] + bl[nf]);
      }
  } else {
    float* C = (float*)Cout;
    const int cg = n0 >> 6;               // wave-uniform column group (768%64==0)
    float bl[4];
#pragma unroll
    for (int nf = 0; nf < 4; ++nf) bl[nf] = bias[n0 + nf * 16 + l15];
#pragma unroll
    for (int mf = 0; mf < 4; ++mf)
#pragma unroll
      for (int r = 0; r < 4; ++r) {
        int row = m0 + mf * 16 + quad * 4 + r;
        int hf = row >> 12;               // 0 -> context_b (q = after), 1 -> context_a
        int m4 = row & 4095;
        int b = m4 >> 10, i = m4 & 1023;
        int j = i * 12 + cg;              // f>>6 where f = i*768+col
        int h = j >> 10, n = j & 1023;    // d = col&63 = nf*16+l15
        const unsigned short* rp =
            qkvr + (size_t)(((hf ^ 1) << 12) + (b << 10) + n) * 2304 + h * 64 + l15;
        size_t base = (size_t)row * ldc + n0 + l15;
#pragma unroll
        for (int nf = 0; nf < 4; ++nf)
          C[base + nf * 16] = acc[mf][nf][r] + bl[nf] + bf2f(rp[nf * 16]);
      }
  }
}

// ---------------------------------------------------------- V transpose ----
// vtg[head(=srchalf*48+b*12+h)][d(64)][key(1024)]  <- qkvr v-section
__global__ __launch_bounds__(256) void k_vt(const unsigned short* __restrict__ qkvr,
                                            unsigned short* __restrict__ vtg) {
  __shared__ __align__(16) unsigned short Ls[64 * 72];
  const int t = threadIdx.x;
  const int kt = blockIdx.x, head = blockIdx.y;
  const int hf = head / 48, bh = head - hf * 48;
  const int b = bh / 12, h = bh - (bh / 12) * 12;
  const size_t row0 = (size_t)(hf * 4096 + b * 1024 + kt * 64);
  const int col = 1536 + h * 64;
#pragma unroll
  for (int c0 = 0; c0 < 2; ++c0) {
    int slot = t + c0 * 256;
    int key = slot >> 3, dg = slot & 7;
    *(u32x4*)(Ls + key * 72 + dg * 8) =
        *(const u32x4*)(qkvr + (row0 + key) * 2304 + col + dg * 8);
  }
  __syncthreads();
#pragma unroll
  for (int c0 = 0; c0 < 2; ++c0) {
    int slot = t + c0 * 256;
    int kg = slot & 7;
    int d = ((slot >> 3) & 7) * 8 + (slot >> 6);  // remap: spreads LDS banks
    unsigned int w[4];
#pragma unroll
    for (int j2 = 0; j2 < 4; ++j2) {
      int kk = kg * 8 + j2 * 2;
      w[j2] = (unsigned int)Ls[kk * 72 + d] | ((unsigned int)Ls[(kk + 1) * 72 + d] << 16);
    }
    u32x4 o = {w[0], w[1], w[2], w[3]};
    *(u32x4*)(vtg + (size_t)head * 65536 + (size_t)d * 1024 + kt * 64 + kg * 8) = o;
  }
}

// -------------------------------------------------------------- attention --
// grid (8, 96): x = 128-row Q tile, y = head-instance (hf*48+b*12+h).
// Static-max softmax (safe: LN'd q,k -> score sigma~1), deferred l-reduction.
// K/V staging: reg prefetch distance 1 + raw lgkm-only barriers.
__global__ __launch_bounds__(256) void k_attn(const unsigned short* __restrict__ qkvr,
                                              const unsigned short* __restrict__ vtg,
                                              unsigned short* __restrict__ ctx) {
  __shared__ __align__(16) unsigned short Ks[64 * 72];      // [key][d]
  __shared__ __align__(16) unsigned short Vt[64 * 72];      // [d][key]
  __shared__ __align__(16) unsigned short Ps[4][32 * 72];   // per wave [qrow][key]
  const int tid = threadIdx.x, lane = tid & 63, w = tid >> 6;
  const int quad = lane >> 4, l15 = lane & 15;
  const int qt = blockIdx.x, hi = blockIdx.y;
  const int hf = hi / 48, bh = hi - hf * 48;
  const int b = bh / 12, h = bh - (bh / 12) * 12;
  const int ihq = hf ^ 1, ihk = hf;
  const size_t qrow0 = (size_t)(ihq * 4096 + b * 1024);
  const int qcol = h * 64, kcol = 768 + h * 64;
  const int r0 = qt * 128 + w * 32;
  const float c1 = 0.125f * 1.44269504088896340736f;  // scale * log2(e)

  // Q fragments resident (A-layout: m=l15, k=quad*8+j)
  bf16x8 aq[2][2];
#pragma unroll
  for (int mf = 0; mf < 2; ++mf)
#pragma unroll
    for (int ks = 0; ks < 2; ++ks)
      aq[mf][ks] = ld16(qkvr + (qrow0 + r0 + mf * 16 + l15) * 2304 + qcol + ks * 32 + quad * 8);

  const unsigned short* ksrc = qkvr + (size_t)(ihk * 4096 + b * 1024) * 2304 + kcol;
  const unsigned short* vsrc = vtg + (size_t)(ihk * 48 + b * 12 + h) * 65536;

  const int srow = tid >> 3, sdg = tid & 7;      // this thread's staging slot
  const int srow2 = (tid + 256) >> 3;            // second slot (same sdg)
  u32x4 rk[2], rv[2];
  auto load_kv = [&](int kt) {
    rk[0] = *(const u32x4*)(ksrc + (size_t)(kt * 64 + srow) * 2304 + sdg * 8);
    rk[1] = *(const u32x4*)(ksrc + (size_t)(kt * 64 + srow2) * 2304 + sdg * 8);
    rv[0] = *(const u32x4*)(vsrc + (size_t)srow * 1024 + kt * 64 + sdg * 8);
    rv[1] = *(const u32x4*)(vsrc + (size_t)srow2 * 1024 + kt * 64 + sdg * 8);
  };
  auto store_kv = [&]() {
    *(u32x4*)(Ks + srow * 72 + sdg * 8) = rk[0];
    *(u32x4*)(Ks + srow2 * 72 + sdg * 8) = rk[1];
    *(u32x4*)(Vt + srow * 72 + sdg * 8) = rv[0];
    *(u32x4*)(Vt + srow2 * 72 + sdg * 8) = rv[1];
  };

  f32x4 O[2][4] = {};
  float lsum[2][4] = {};

  load_kv(0);
  store_kv();
  barrier_lds();

  for (int kt = 0; kt < 16; ++kt) {
    if (kt + 1 < 16) load_kv(kt + 1);     // in flight across the compute

    // S = Q K^T
    f32x4 s[2][4] = {};
#pragma unroll
    for (int ks = 0; ks < 2; ++ks)
#pragma unroll
      for (int nf = 0; nf < 4; ++nf) {
        bf16x8 bk = ld16(Ks + (nf * 16 + l15) * 72 + ks * 32 + quad * 8);
        s[0][nf] = MFMA16(aq[0][ks], bk, s[0][nf]);
        s[1][nf] = MFMA16(aq[1][ks], bk, s[1][nf]);
      }

    // static-max softmax: p = 2^(s*c1); per-lane partial sums only
    unsigned short* myP = Ps[w];
#pragma unroll
    for (int mf = 0; mf < 2; ++mf)
#pragma unroll
      for (int r = 0; r < 4; ++r) {
        float p0 = __builtin_amdgcn_exp2f(s[mf][0][r] * c1);
        float p1 = __builtin_amdgcn_exp2f(s[mf][1][r] * c1);
        float p2 = __builtin_amdgcn_exp2f(s[mf][2][r] * c1);
        float p3 = __builtin_amdgcn_exp2f(s[mf][3][r] * c1);
        lsum[mf][r] += (p0 + p1) + (p2 + p3);
        int rowq = (mf * 16 + quad * 4 + r) * 72 + l15;
        myP[rowq]      = f2bf(p0);
        myP[rowq + 16] = f2bf(p1);
        myP[rowq + 32] = f2bf(p2);
        myP[rowq + 48] = f2bf(p3);
      }

    // O += P V
#pragma unroll
    for (int k2 = 0; k2 < 2; ++k2) {
      bf16x8 pa0 = ld16(myP + l15 * 72 + k2 * 32 + quad * 8);
      bf16x8 pa1 = ld16(myP + (16 + l15) * 72 + k2 * 32 + quad * 8);
#pragma unroll
      for (int df = 0; df < 4; ++df) {
        bf16x8 bv = ld16(Vt + (df * 16 + l15) * 72 + k2 * 32 + quad * 8);
        O[0][df] = MFMA16(pa0, bv, O[0][df]);
        O[1][df] = MFMA16(pa1, bv, O[1][df]);
      }
    }

    barrier_lds();                        // all waves done reading Ks/Vt
    if (kt + 1 < 16) {
      store_kv();                         // vmcnt wait here (hidden by compute)
      barrier_lds();
    }
  }

  // epilogue: reduce l across the 16-lane row group, scale, store
#pragma unroll
  for (int mf = 0; mf < 2; ++mf)
#pragma unroll
    for (int r = 0; r < 4; ++r) {
      float l = lsum[mf][r];
#pragma unroll
      for (int o = 1; o < 16; o <<= 1) l += __shfl_xor(l, o);
      float inv = 1.0f / l;
      int n = r0 + mf * 16 + quad * 4 + r;
      size_t orow = (size_t)(hf * 4096 + b * 1024 + n) * 768 + h * 64;
#pragma unroll
      for (int df = 0; df < 4; ++df)
        ctx[orow + df * 16 + l15] = f2bf(O[mf][df][r] * inv);
    }
}

// ------------------------------------------------------------------ launch --
extern "C" void kernel_launch(void* const* d_in, const int* in_sizes, int n_in,
                              void* d_out, int out_size, void* d_ws, size_t ws_size,
                              hipStream_t stream) {
  (void)in_sizes; (void)n_in; (void)out_size; (void)ws_size;
  const float* before = (const float*)d_in[0];
  const float* after  = (const float*)d_in[1];
  const float* wqkv   = (const float*)d_in[2];
  const float* lng    = (const float*)d_in[3];
  const float* lnb    = (const float*)d_in[4];
  const float* wproj  = (const float*)d_in[5];
  const float* bproj  = (const float*)d_in[6];
  float* out = (float*)d_out;
  unsigned short* ws = (unsigned short*)d_ws;
  unsigned short* xb     = ws;
  unsigned short* vtg    = ws;             // reuses xb after gemm0
  unsigned short* wqkvb  = ws + 6291456;
  unsigned short* wprojb = ws + 8060928;
  unsigned short* qkvr   = ws + 8650752;
  unsigned short* ctx    = ws + 27525120;

  k_convert<<<8448, 256, 0, stream>>>(before, after, wqkv, wproj, ws);
  k_gemm<768, 0><<<dim3(9, 128), 256, 0, stream>>>(
      xb, wqkvb, (void*)qkvr, nullptr, nullptr, lng, lnb, 2304);
  k_vt<<<dim3(16, 96), 256, 0, stream>>>(qkvr, vtg);
  k_attn<<<dim3(8, 96), 256, 0, stream>>>(qkvr, vtg, ctx);
  k_gemm<768, 1><<<dim3(3, 128), 256, 0, stream>>>(
      ctx, wprojb, (void*)out, qkvr, bproj, nullptr, nullptr, 768);
}

// Round 6
// 292.700 us; speedup vs baseline: 1.0455x; 1.0455x over previous
//
#include <hip/hip_runtime.h>

// ---------------------------------------------------------------------------
// Fused: qkv-proj + head-LN -> cross-attention (x2) -> proj.
// B=4, N=1024, C=768, H=12, HD=64.  MFMA bf16 16x16x32, f32 accum.
//
// KEY IDEA (round 6): all bf16 tensors live in FRAGMENT-TILED layout:
//   elem(m,k) -> ((m>>4)*(K/8) + (k>>3))*128 + (m&15)*8 + (k&7)
// so every MFMA A/B fragment load is ONE contiguous 1KB wave transaction
// (8 cache lines).  Rounds 3-5 were L2-request-rate bound: rowwise-per-lane
// loads shattered into 16-64 lines/instr (~360G lines/s > L2 ceiling).
// With tiled layouts the GEMMs and attention are BARRIER-FREE (frags direct
// global->reg; no LDS staging except the per-wave P round-trip and k_vt).
//
// ws layout (ushort elements), all K=768 tensors have 96 k-chunks:
//   xbt  @ 0        : tiled [8192 x 768]   (rows 0..4095 before, rest after)
//   (vtg @ 0        : 96 heads x tiled [64 d x 1024 key] -- reuses xbt)
//   wqt  @ 6291456  : tiled [2304 x 768]
//   wpt  @ 8060928  : tiled [768 x 768]
//   qkvr @ 8650752  : tiled [8192 x 2304] post-LN qkv (288 k-chunks)
//   ctx  @ 27525120 : tiled [8192 x 768]
// ---------------------------------------------------------------------------

typedef __bf16 bf16x8 __attribute__((ext_vector_type(8)));
typedef float  f32x4  __attribute__((ext_vector_type(4)));
typedef unsigned int u32x4 __attribute__((ext_vector_type(4)));
typedef unsigned short us;

#define MFMA16(a, b, c) __builtin_amdgcn_mfma_f32_16x16x32_bf16(a, b, c, 0, 0, 0)

__device__ __forceinline__ us f2bf(float f) {
  unsigned int u = __builtin_bit_cast(unsigned int, f);
  u += 0x7FFFu + ((u >> 16) & 1u);   // RNE
  return (us)(u >> 16);
}
__device__ __forceinline__ float bf2f(us h) {
  unsigned int u = ((unsigned int)h) << 16;
  return __builtin_bit_cast(float, u);
}
__device__ __forceinline__ bf16x8 ld16(const us* p) {
  return __builtin_bit_cast(bf16x8, *(const u32x4*)p);
}

// ---------------------------------------------------------------- convert --
// f32 row-major -> bf16 fragment-tiled.  One 16B tiled piece per thread.
__global__ __launch_bounds__(256) void k_convert(
    const float* __restrict__ before, const float* __restrict__ after,
    const float* __restrict__ wqkv, const float* __restrict__ wproj,
    us* __restrict__ ws) {
  int t = blockIdx.x * 256 + threadIdx.x;
  us* dst; int u;
  if (t < 786432)       { u = t;           dst = ws; }
  else if (t < 1007616) { u = t - 786432;  dst = ws + 6291456; }
  else                  { u = t - 1007616; dst = ws + 8060928; }
  int l15 = u & 15, c2 = u >> 4;
  int kc = c2 % 96, mt = c2 / 96;
  int row = mt * 16 + l15;
  const float* srow;
  if (t < 786432)       srow = row < 4096 ? before + (size_t)row * 768
                                          : after + (size_t)(row - 4096) * 768;
  else if (t < 1007616) srow = wqkv + (size_t)row * 768;
  else                  srow = wproj + (size_t)row * 768;
  const float4* s4 = (const float4*)(srow + kc * 8);
  float4 a = s4[0], b = s4[1];
  union { u32x4 v; us s[8]; } o;
  o.s[0] = f2bf(a.x); o.s[1] = f2bf(a.y); o.s[2] = f2bf(a.z); o.s[3] = f2bf(a.w);
  o.s[4] = f2bf(b.x); o.s[5] = f2bf(b.y); o.s[6] = f2bf(b.z); o.s[7] = f2bf(b.w);
  *(u32x4*)(dst + (size_t)c2 * 128 + l15 * 8) = o.v;
}

// -------------------------------------------------------------- gemm core --
// Barrier-free NT GEMM, wave tile 64x64 (4x4 frags), tiled operands,
// 3-stage register pipeline.  Ab/Bb pre-offset with mtile base + l15*8.
template <int K>
__device__ __forceinline__ void gemm_core(const us* __restrict__ Ab,
                                          const us* __restrict__ Bb,
                                          int quad, f32x4 acc[4][4]) {
  constexpr int KC = K / 8, NS = K / 32;
  bf16x8 af[3][4], bfv[3][4];
  auto loadf = [&](int s, int k0) {
#pragma unroll
    for (int f = 0; f < 4; ++f) {
      af[s][f]  = ld16(Ab + ((size_t)f * KC + (k0 >> 3) + quad) * 128);
      bfv[s][f] = ld16(Bb + ((size_t)f * KC + (k0 >> 3) + quad) * 128);
    }
  };
  loadf(0, 0);
  loadf(1, 32);
#pragma unroll
  for (int it = 0; it < NS; ++it) {
    const int p = it % 3;
    if (it + 2 < NS) loadf((it + 2) % 3, (it + 2) * 32);
#pragma unroll
    for (int mf = 0; mf < 4; ++mf)
#pragma unroll
      for (int nf = 0; nf < 4; ++nf)
        acc[mf][nf] = MFMA16(af[p][mf], bfv[p][nf], acc[mf][nf]);
  }
}

// --------------------------------------------------------------- gemm qkv --
// grid (9,128): n0 = (bx*4+w)*64, m0 = by*64.  Per-head LN epilogue, writes
// qkvr TILED (288 k-chunks).
__global__ __launch_bounds__(256) void k_gemm_qkv(
    const us* __restrict__ A, const us* __restrict__ B, us* __restrict__ C,
    const float* __restrict__ g, const float* __restrict__ bb) {
  const int lane = threadIdx.x & 63, w = threadIdx.x >> 6;
  const int quad = lane >> 4, l15 = lane & 15;
  const int m0 = blockIdx.y * 64, n0 = (blockIdx.x * 4 + w) * 64;
  const us* Ab = A + (size_t)(m0 >> 4) * 96 * 128 + l15 * 8;
  const us* Bb = B + (size_t)(n0 >> 4) * 96 * 128 + l15 * 8;
  f32x4 acc[4][4] = {};
  gemm_core<768>(Ab, Bb, quad, acc);

  float gl[4], bl[4];
#pragma unroll
  for (int nf = 0; nf < 4; ++nf) { gl[nf] = g[nf * 16 + l15]; bl[nf] = bb[nf * 16 + l15]; }
#pragma unroll
  for (int mf = 0; mf < 4; ++mf)
#pragma unroll
    for (int r = 0; r < 4; ++r) {
      float s1 = acc[mf][0][r] + acc[mf][1][r] + acc[mf][2][r] + acc[mf][3][r];
      float s2 = acc[mf][0][r] * acc[mf][0][r] + acc[mf][1][r] * acc[mf][1][r]
               + acc[mf][2][r] * acc[mf][2][r] + acc[mf][3][r] * acc[mf][3][r];
#pragma unroll
      for (int o = 1; o < 16; o <<= 1) { s1 += __shfl_xor(s1, o); s2 += __shfl_xor(s2, o); }
      float mu = s1 * (1.0f / 64.0f);
      float var = s2 * (1.0f / 64.0f) - mu * mu;
      float sc = rsqrtf(var + 1e-5f);
      size_t cb = ((size_t)(m0 / 16 + mf) * 288 + (n0 >> 3) + (l15 >> 3)) * 128
                + (quad * 4 + r) * 8 + (l15 & 7);
#pragma unroll
      for (int nf = 0; nf < 4; ++nf)
        C[cb + nf * 256] = f2bf((acc[mf][nf][r] - mu) * sc * gl[nf] + bl[nf]);
    }
}

// -------------------------------------------------------------- gemm proj --
// grid (3,128).  f32 row-major out + bias + untransposed-q residual (from
// tiled qkvr).
__global__ __launch_bounds__(256) void k_gemm_proj(
    const us* __restrict__ A, const us* __restrict__ B, float* __restrict__ C,
    const us* __restrict__ qkvr, const float* __restrict__ bias) {
  const int lane = threadIdx.x & 63, w = threadIdx.x >> 6;
  const int quad = lane >> 4, l15 = lane & 15;
  const int m0 = blockIdx.y * 64, n0 = (blockIdx.x * 4 + w) * 64;
  const us* Ab = A + (size_t)(m0 >> 4) * 96 * 128 + l15 * 8;
  const us* Bb = B + (size_t)(n0 >> 4) * 96 * 128 + l15 * 8;
  f32x4 acc[4][4] = {};
  gemm_core<768>(Ab, Bb, quad, acc);

  const int cg = n0 >> 6;                 // wave-uniform column group
  float bl[4];
#pragma unroll
  for (int nf = 0; nf < 4; ++nf) bl[nf] = bias[n0 + nf * 16 + l15];
#pragma unroll
  for (int mf = 0; mf < 4; ++mf)
#pragma unroll
    for (int r = 0; r < 4; ++r) {
      int row = m0 + mf * 16 + quad * 4 + r;
      int hf = row >> 12;                 // 0 -> context_b (q=after), 1 -> context_a
      int m4 = row & 4095;
      int b = m4 >> 10, i = m4 & 1023;
      int j = i * 12 + cg;                // f>>6 where f = i*768+col
      int h = j >> 10, n = j & 1023;      // d = nf*16 + l15
      int qrow = ((hf ^ 1) << 12) + (b << 10) + n;
      size_t rb = ((size_t)(qrow >> 4) * 288 + h * 8 + (l15 >> 3)) * 128
                + (qrow & 15) * 8 + (l15 & 7);
      size_t base = (size_t)row * 768 + n0 + l15;
#pragma unroll
      for (int nf = 0; nf < 4; ++nf)
        C[base + nf * 16] = acc[mf][nf][r] + bl[nf] + bf2f(qkvr[rb + nf * 256]);
    }
}

// ---------------------------------------------------------- V transpose ----
// vtg: per head hi (=srchalf*48+b*12+h), tiled [64 d x 1024 key].
__global__ __launch_bounds__(256) void k_vt(const us* __restrict__ qkvr,
                                            us* __restrict__ vtg) {
  __shared__ us Ls[64 * 72];
  const int t = threadIdx.x;
  const int kt = blockIdx.x, hi = blockIdx.y;
  const int hf = hi / 48, bh = hi - hf * 48;
  const int b = bh / 12, h = bh - (bh / 12) * 12;
  const int qb16 = (hf * 4096 + b * 1024 + kt * 64) >> 4;
#pragma unroll
  for (int c0 = 0; c0 < 2; ++c0) {
    int slot = t + c0 * 256;
    int key = slot & 63, c = slot >> 6;   // c wave-uniform-ish, keys coalesced
    size_t src = ((size_t)(qb16 + (key >> 4)) * 288 + 192 + h * 8 + c) * 128
               + (key & 15) * 8;
    *(u32x4*)(Ls + key * 72 + c * 8) = *(const u32x4*)(qkvr + src);
  }
  __syncthreads();
  us* vb = vtg + (size_t)hi * 65536;
#pragma unroll
  for (int c0 = 0; c0 < 2; ++c0) {
    int slot = t + c0 * 256;
    int d = (slot & 7) + ((slot >> 6) << 3);
    int kg = (slot >> 3) & 7;
    union { u32x4 v; us s[8]; } o;
#pragma unroll
    for (int j = 0; j < 8; ++j) o.s[j] = Ls[(kg * 8 + j) * 72 + d];
    *(u32x4*)(vb + ((size_t)(d >> 4) * 128 + kt * 8 + kg) * 128 + (d & 15) * 8) = o.v;
  }
}

// -------------------------------------------------------------- attention --
// grid (8,96).  BARRIER-FREE: Q/K/V fragments read directly from tiled
// global (1KB coalesced); only LDS use is the per-wave P round-trip.
// Static-max softmax (LN'd q,k -> scores bounded), deferred l-reduction.
__global__ __launch_bounds__(256) void k_attn(const us* __restrict__ qkvr,
                                              const us* __restrict__ vtg,
                                              us* __restrict__ ctx) {
  __shared__ us Ps[4][32 * 72];
  const int tid = threadIdx.x, lane = tid & 63, w = tid >> 6;
  const int quad = lane >> 4, l15 = lane & 15;
  const int qt = blockIdx.x, hi = blockIdx.y;
  const int hf = hi / 48, bh = hi - hf * 48;
  const int b = bh / 12, h = bh - (bh / 12) * 12;
  const int ihq = hf ^ 1, ihk = hf;
  const int r0 = qt * 128 + w * 32;
  const int qmt = (ihq * 4096 + b * 1024 + r0) >> 4;
  const int kb16 = (ihk * 4096 + b * 1024) >> 4;
  const us* vbase = vtg + (size_t)(ihk * 48 + b * 12 + h) * 65536;
  const float c1 = 0.125f * 1.44269504088896340736f;  // scale * log2(e)

  // Q fragments resident (A-layout)
  bf16x8 aq[2][2];
#pragma unroll
  for (int mf = 0; mf < 2; ++mf)
#pragma unroll
    for (int ks = 0; ks < 2; ++ks)
      aq[mf][ks] = ld16(qkvr + ((size_t)(qmt + mf) * 288 + h * 8 + ks * 4 + quad) * 128
                        + l15 * 8);

  f32x4 O[2][4] = {};
  float lsum[2][4] = {};
  us* myP = Ps[w];

  for (int kt = 0; kt < 16; ++kt) {
    const int kmt = kb16 + kt * 4;
    bf16x8 bk[4][2], bv[4][2];
#pragma unroll
    for (int nf = 0; nf < 4; ++nf)
#pragma unroll
      for (int ks = 0; ks < 2; ++ks)
        bk[nf][ks] = ld16(qkvr + ((size_t)(kmt + nf) * 288 + 96 + h * 8 + ks * 4 + quad) * 128
                          + l15 * 8);
#pragma unroll
    for (int df = 0; df < 4; ++df)
#pragma unroll
      for (int k2 = 0; k2 < 2; ++k2)
        bv[df][k2] = ld16(vbase + ((size_t)df * 128 + kt * 8 + k2 * 4 + quad) * 128
                          + l15 * 8);

    // S = Q K^T
    f32x4 s[2][4] = {};
#pragma unroll
    for (int ks = 0; ks < 2; ++ks)
#pragma unroll
      for (int nf = 0; nf < 4; ++nf) {
        s[0][nf] = MFMA16(aq[0][ks], bk[nf][ks], s[0][nf]);
        s[1][nf] = MFMA16(aq[1][ks], bk[nf][ks], s[1][nf]);
      }

    // static-max softmax; per-lane partial l sums
#pragma unroll
    for (int mf = 0; mf < 2; ++mf)
#pragma unroll
      for (int r = 0; r < 4; ++r) {
        float p0 = __builtin_amdgcn_exp2f(s[mf][0][r] * c1);
        float p1 = __builtin_amdgcn_exp2f(s[mf][1][r] * c1);
        float p2 = __builtin_amdgcn_exp2f(s[mf][2][r] * c1);
        float p3 = __builtin_amdgcn_exp2f(s[mf][3][r] * c1);
        lsum[mf][r] += (p0 + p1) + (p2 + p3);
        int rowq = (mf * 16 + quad * 4 + r) * 72 + l15;
        myP[rowq]      = f2bf(p0);
        myP[rowq + 16] = f2bf(p1);
        myP[rowq + 32] = f2bf(p2);
        myP[rowq + 48] = f2bf(p3);
      }

    // O += P V   (per-wave LDS round-trip; same-wave ordering is implicit)
#pragma unroll
    for (int k2 = 0; k2 < 2; ++k2) {
      bf16x8 pa0 = ld16(myP + l15 * 72 + k2 * 32 + quad * 8);
      bf16x8 pa1 = ld16(myP + (16 + l15) * 72 + k2 * 32 + quad * 8);
#pragma unroll
      for (int df = 0; df < 4; ++df) {
        O[0][df] = MFMA16(pa0, bv[df][k2], O[0][df]);
        O[1][df] = MFMA16(pa1, bv[df][k2], O[1][df]);
      }
    }
  }

  // epilogue: l-reduction, scale, store ctx TILED (96 k-chunks)
  const int omt = (hf * 4096 + b * 1024 + r0) >> 4;
#pragma unroll
  for (int mf = 0; mf < 2; ++mf)
#pragma unroll
    for (int r = 0; r < 4; ++r) {
      float l = lsum[mf][r];
#pragma unroll
      for (int o = 1; o < 16; o <<= 1) l += __shfl_xor(l, o);
      float inv = 1.0f / l;
      size_t cb = ((size_t)(omt + mf) * 96 + h * 8 + (l15 >> 3)) * 128
                + (quad * 4 + r) * 8 + (l15 & 7);
#pragma unroll
      for (int df = 0; df < 4; ++df)
        ctx[cb + df * 256] = f2bf(O[mf][df][r] * inv);
    }
}

// ------------------------------------------------------------------ launch --
extern "C" void kernel_launch(void* const* d_in, const int* in_sizes, int n_in,
                              void* d_out, int out_size, void* d_ws, size_t ws_size,
                              hipStream_t stream) {
  (void)in_sizes; (void)n_in; (void)out_size; (void)ws_size;
  const float* before = (const float*)d_in[0];
  const float* after  = (const float*)d_in[1];
  const float* wqkv   = (const float*)d_in[2];
  const float* lng    = (const float*)d_in[3];
  const float* lnb    = (const float*)d_in[4];
  const float* wproj  = (const float*)d_in[5];
  const float* bproj  = (const float*)d_in[6];
  float* out = (float*)d_out;
  us* ws  = (us*)d_ws;
  us* xbt = ws;
  us* vtg = ws;                      // reuses xbt after gemm_qkv
  us* wqt = ws + 6291456;
  us* wpt = ws + 8060928;
  us* qkvr = ws + 8650752;
  us* ctx  = ws + 27525120;

  k_convert<<<4224, 256, 0, stream>>>(before, after, wqkv, wproj, ws);
  k_gemm_qkv<<<dim3(9, 128), 256, 0, stream>>>(xbt, wqt, qkvr, lng, lnb);
  k_vt<<<dim3(16, 96), 256, 0, stream>>>(qkvr, vtg);
  k_attn<<<dim3(8, 96), 256, 0, stream>>>(qkvr, vtg, ctx);
  k_gemm_proj<<<dim3(3, 128), 256, 0, stream>>>(ctx, wpt, out, qkvr, bproj);
}

// Round 7
// 212.432 us; speedup vs baseline: 1.4405x; 1.3779x over previous
//
#include <hip/hip_runtime.h>

// ---------------------------------------------------------------------------
// Fused: qkv-proj + head-LN -> cross-attention (x2) -> proj.
// B=4, N=1024, C=768, H=12, HD=64.  MFMA bf16 16x16x32, f32 accum.
//
// Round-7 synthesis of measured-best pieces:
//  * fragment-tiled bf16 layout everywhere: elem(m,k) ->
//      ((m>>4)*(K/8) + (k>>3))*128 + (m&15)*8 + (k&7)
//    -> every global load is ONE contiguous 1KB wave transaction.
//  * GEMM/attention use the r3 reg->LDS single-buffered pipeline (measured
//    best) with identity LDS staging into 272B-padded chunks (bank-dispersed,
//    zero repack VALU).  LDS sharing kills the 4x per-wave duplication that
//    made barrier-free r5/r6 L3-bandwidth-bound.
//  * XCD-aware grids: data-sharing blocks get equal linear%8.
//      gemm: grid(x=m-tile, y=n-tile) -> same-A blocks co-XCD.
//      vt/attn: grid(x=head-instance, y=·) -> per-head K/V stays L2-hot
//      (12 heads x 256KB = 3MB < 4MB per-XCD L2).
//
// ws layout (ushort elements):
//   xbt  @ 0        : tiled [8192 x 768]  (rows 0..4095 before, rest after)
//   (vtg @ 0        : 96 heads x tiled [64 d x 1024 key] -- reuses xbt)
//   wqt  @ 6291456  : tiled [2304 x 768]
//   wpt  @ 8060928  : tiled [768 x 768]
//   qkvr @ 8650752  : tiled [8192 x 2304] post-LN qkv (288 k-chunks)
//   ctx  @ 27525120 : tiled [8192 x 768]
// ---------------------------------------------------------------------------

typedef __bf16 bf16x8 __attribute__((ext_vector_type(8)));
typedef float  f32x4  __attribute__((ext_vector_type(4)));
typedef unsigned int u32x4 __attribute__((ext_vector_type(4)));
typedef unsigned short us;

#define MFMA16(a, b, c) __builtin_amdgcn_mfma_f32_16x16x32_bf16(a, b, c, 0, 0, 0)

__device__ __forceinline__ us f2bf(float f) {
  unsigned int u = __builtin_bit_cast(unsigned int, f);
  u += 0x7FFFu + ((u >> 16) & 1u);   // RNE
  return (us)(u >> 16);
}
__device__ __forceinline__ float bf2f(us h) {
  unsigned int u = ((unsigned int)h) << 16;
  return __builtin_bit_cast(float, u);
}
__device__ __forceinline__ bf16x8 ld16(const us* p) {
  return __builtin_bit_cast(bf16x8, *(const u32x4*)p);
}

// LDS chunk stride: 128 elems payload padded to 136 (272 B, 16B-aligned,
// 68 words ≡ 4 mod 32 -> quad-adjacent chunks hit shifted banks).
#define CH 136

// ---------------------------------------------------------------- convert --
// f32 row-major -> bf16 fragment-tiled.  One 16B tiled piece per thread.
__global__ __launch_bounds__(256) void k_convert(
    const float* __restrict__ before, const float* __restrict__ after,
    const float* __restrict__ wqkv, const float* __restrict__ wproj,
    us* __restrict__ ws) {
  int t = blockIdx.x * 256 + threadIdx.x;
  us* dst; int u;
  if (t < 786432)       { u = t;           dst = ws; }
  else if (t < 1007616) { u = t - 786432;  dst = ws + 6291456; }
  else                  { u = t - 1007616; dst = ws + 8060928; }
  int l15 = u & 15, c2 = u >> 4;
  int kc = c2 % 96, mt = c2 / 96;
  int row = mt * 16 + l15;
  const float* srow;
  if (t < 786432)       srow = row < 4096 ? before + (size_t)row * 768
                                          : after + (size_t)(row - 4096) * 768;
  else if (t < 1007616) srow = wqkv + (size_t)row * 768;
  else                  srow = wproj + (size_t)row * 768;
  const float4* s4 = (const float4*)(srow + kc * 8);
  float4 a = s4[0], b = s4[1];
  union { u32x4 v; us s[8]; } o;
  o.s[0] = f2bf(a.x); o.s[1] = f2bf(a.y); o.s[2] = f2bf(a.z); o.s[3] = f2bf(a.w);
  o.s[4] = f2bf(b.x); o.s[5] = f2bf(b.y); o.s[6] = f2bf(b.z); o.s[7] = f2bf(b.w);
  *(u32x4*)(dst + (size_t)c2 * 128 + l15 * 8) = o.v;
}

// ------------------------------------------------------------------- GEMM --
// NT GEMM on tiled operands.  Block tile MT x 128, 4 waves (2x2), K=768.
// reg->LDS single-buffer pipeline (r3 structure): prefetch tile it+1 into
// regs during compute of tile it.  All loads 1KB coalesced; LDS = identity
// chunk copy.  grid(x = m-tile, y = n-tile) -> XCD = m%8 (A co-XCD).
// MODE 0: per-head LayerNorm epilogue, tiled bf16 out (qkvr, 288 chunks).
// MODE 1: f32 row-major out + bias + untransposed-q residual.
template <int MT, int MODE>
__global__ __launch_bounds__(256) void k_gemm(
    const us* __restrict__ A, const us* __restrict__ B, void* __restrict__ Cout,
    const us* __restrict__ qkvr, const float* __restrict__ bias,
    const float* __restrict__ g, const float* __restrict__ bb) {
  constexpr int MC = MT / 16;               // m-chunks per tile (8 or 4)
  constexpr int AJ = MC / 2;                // A reg-units per wave (4 or 2)
  constexpr int NITER = 12;                 // K=768, BK=64
  __shared__ us As[MC * 8 * CH];
  __shared__ us Bs[64 * CH];
  const int tid = threadIdx.x, lane = tid & 63, w = tid >> 6;
  const int quad = lane >> 4, l15 = lane & 15;
  const int m0 = blockIdx.x * MT, n0 = blockIdx.y * 128;
  const int wm = (w >> 1) * (MT / 2), wn = (w & 1) * 64;
  f32x4 acc[AJ][4] = {};
  u32x4 ra[AJ], rb[4];

  auto load_regs = [&](int k0) {
#pragma unroll
    for (int j = 0; j < AJ; ++j) {
      int u = w * AJ + j;
      ra[j] = *(const u32x4*)(A + ((size_t)((m0 >> 4) + (u >> 1)) * 96
                                   + (k0 >> 3) + (u & 1) * 4) * 128 + lane * 8);
    }
#pragma unroll
    for (int j = 0; j < 4; ++j) {
      int u = w * 4 + j;
      rb[j] = *(const u32x4*)(B + ((size_t)((n0 >> 4) + (u >> 1)) * 96
                                   + (k0 >> 3) + (u & 1) * 4) * 128 + lane * 8);
    }
  };
  auto store_regs = [&]() {
#pragma unroll
    for (int j = 0; j < AJ; ++j) {
      int slot = (w * AJ + j) * 4 + (lane >> 4);
      *(u32x4*)(As + slot * CH + l15 * 8) = ra[j];
    }
#pragma unroll
    for (int j = 0; j < 4; ++j) {
      int slot = (w * 4 + j) * 4 + (lane >> 4);
      *(u32x4*)(Bs + slot * CH + l15 * 8) = rb[j];
    }
  };

  load_regs(0);
  store_regs();
  __syncthreads();

#pragma unroll
  for (int it = 0; it < NITER; ++it) {
    if (it + 1 < NITER) load_regs((it + 1) * 64);
#pragma unroll
    for (int ks = 0; ks < 2; ++ks) {
      bf16x8 af[AJ], bfr[4];
#pragma unroll
      for (int mf = 0; mf < AJ; ++mf)
        af[mf] = ld16(As + (((wm >> 4) + mf) * 8 + ks * 4 + quad) * CH + l15 * 8);
#pragma unroll
      for (int nf = 0; nf < 4; ++nf)
        bfr[nf] = ld16(Bs + (((wn >> 4) + nf) * 8 + ks * 4 + quad) * CH + l15 * 8);
#pragma unroll
      for (int mf = 0; mf < AJ; ++mf)
#pragma unroll
        for (int nf = 0; nf < 4; ++nf)
          acc[mf][nf] = MFMA16(af[mf], bfr[nf], acc[mf][nf]);
    }
    __syncthreads();
    if (it + 1 < NITER) {
      store_regs();
      __syncthreads();
    }
  }

  if (MODE == 0) {
    // per-head LayerNorm: wave's 64 cols = exactly one (s,h) group
    us* C = (us*)Cout;
    float gl[4], bl[4];
#pragma unroll
    for (int nf = 0; nf < 4; ++nf) { gl[nf] = g[nf * 16 + l15]; bl[nf] = bb[nf * 16 + l15]; }
#pragma unroll
    for (int mf = 0; mf < AJ; ++mf)
#pragma unroll
      for (int r = 0; r < 4; ++r) {
        float s1 = acc[mf][0][r] + acc[mf][1][r] + acc[mf][2][r] + acc[mf][3][r];
        float s2 = acc[mf][0][r] * acc[mf][0][r] + acc[mf][1][r] * acc[mf][1][r]
                 + acc[mf][2][r] * acc[mf][2][r] + acc[mf][3][r] * acc[mf][3][r];
#pragma unroll
        for (int o = 1; o < 16; o <<= 1) { s1 += __shfl_xor(s1, o); s2 += __shfl_xor(s2, o); }
        float mu = s1 * (1.0f / 64.0f);
        float var = s2 * (1.0f / 64.0f) - mu * mu;
        float sc = rsqrtf(var + 1e-5f);
        size_t cb = ((size_t)(((m0 + wm) >> 4) + mf) * 288 + ((n0 + wn) >> 3)
                     + (l15 >> 3)) * 128 + (quad * 4 + r) * 8 + (l15 & 7);
#pragma unroll
        for (int nf = 0; nf < 4; ++nf)
          C[cb + nf * 256] = f2bf((acc[mf][nf][r] - mu) * sc * gl[nf] + bl[nf]);
      }
  } else {
    float* C = (float*)Cout;
    const int cg = (n0 + wn) >> 6;          // wave-uniform column group
    float bl[4];
#pragma unroll
    for (int nf = 0; nf < 4; ++nf) bl[nf] = bias[n0 + wn + nf * 16 + l15];
#pragma unroll
    for (int mf = 0; mf < AJ; ++mf)
#pragma unroll
      for (int r = 0; r < 4; ++r) {
        int row = m0 + wm + mf * 16 + quad * 4 + r;
        int hf = row >> 12;                 // 0 -> context_b (q=after), 1 -> context_a
        int m4 = row & 4095;
        int b = m4 >> 10, i = m4 & 1023;
        int j = i * 12 + cg;                // f>>6 where f = i*768+col
        int h = j >> 10, n = j & 1023;      // d = nf*16 + l15
        int qrow = ((hf ^ 1) << 12) + (b << 10) + n;
        size_t rb2 = ((size_t)(qrow >> 4) * 288 + h * 8 + (l15 >> 3)) * 128
                   + (qrow & 15) * 8 + (l15 & 7);
        size_t base = (size_t)row * 768 + n0 + wn + l15;
#pragma unroll
        for (int nf = 0; nf < 4; ++nf)
          C[base + nf * 16] = acc[mf][nf][r] + bl[nf] + bf2f(qkvr[rb2 + nf * 256]);
      }
  }
}

// ---------------------------------------------------------- V transpose ----
// vtg: per head hi (=srchalf*48+b*12+h), tiled [64 d x 1024 key].
// grid (96 hi, 16 kt) -> XCD = hi%8, matching k_attn consumers.
__global__ __launch_bounds__(256) void k_vt(const us* __restrict__ qkvr,
                                            us* __restrict__ vtg) {
  __shared__ us Ls[64 * 72];
  const int t = threadIdx.x;
  const int hi = blockIdx.x, kt = blockIdx.y;
  const int hf = hi / 48, bh = hi - hf * 48;
  const int b = bh / 12, h = bh - (bh / 12) * 12;
  const int qb16 = (hf * 4096 + b * 1024 + kt * 64) >> 4;
#pragma unroll
  for (int c0 = 0; c0 < 2; ++c0) {
    int slot = t + c0 * 256;
    int key = slot & 63, c = slot >> 6;
    size_t src = ((size_t)(qb16 + (key >> 4)) * 288 + 192 + h * 8 + c) * 128
               + (key & 15) * 8;
    *(u32x4*)(Ls + key * 72 + c * 8) = *(const u32x4*)(qkvr + src);
  }
  __syncthreads();
  us* vb = vtg + (size_t)hi * 65536;
#pragma unroll
  for (int c0 = 0; c0 < 2; ++c0) {
    int slot = t + c0 * 256;
    int d = (slot & 7) + ((slot >> 6) << 3);
    int kg = (slot >> 3) & 7;
    union { u32x4 v; us s[8]; } o;
#pragma unroll
    for (int j = 0; j < 8; ++j) o.s[j] = Ls[(kg * 8 + j) * 72 + d];
    *(u32x4*)(vb + ((size_t)(d >> 4) * 128 + kt * 8 + kg) * 128 + (d & 15) * 8) = o.v;
  }
}

// -------------------------------------------------------------- attention --
// grid (96 hi, 8 qt) -> XCD = hi%8: all blocks of one head co-XCD, K/V
// (256KB/head, 12 heads/XCD = 3MB) stays L2-hot.  K/V staged through LDS
// (block-shared, kills 4x duplication) with reg prefetch distance 1.
// Static-max softmax (LN'd q,k), deferred l-reduction.
__global__ __launch_bounds__(256) void k_attn(const us* __restrict__ qkvr,
                                              const us* __restrict__ vtg,
                                              us* __restrict__ ctx) {
  __shared__ us Ks[32 * CH];                // K tile: 4 keychunks x 8 dchunks
  __shared__ us Vt[32 * CH];                // V^T tile: 4 dchunks x 8 keychunks
  __shared__ us Ps[4][32 * 72];             // per wave [qrow][key]
  const int tid = threadIdx.x, lane = tid & 63, w = tid >> 6;
  const int quad = lane >> 4, l15 = lane & 15;
  const int hi = blockIdx.x, qt = blockIdx.y;
  const int hf = hi / 48, bh = hi - hf * 48;
  const int b = bh / 12, h = bh - (bh / 12) * 12;
  const int ihq = hf ^ 1, ihk = hf;
  const int r0 = qt * 128 + w * 32;
  const int qmt = (ihq * 4096 + b * 1024 + r0) >> 4;
  const int kb16 = (ihk * 4096 + b * 1024) >> 4;
  const us* vbase = vtg + (size_t)(ihk * 48 + b * 12 + h) * 65536;
  const float c1 = 0.125f * 1.44269504088896340736f;  // scale * log2(e)

  // Q fragments resident (A-layout), direct from tiled global
  bf16x8 aq[2][2];
#pragma unroll
  for (int mf = 0; mf < 2; ++mf)
#pragma unroll
    for (int ks = 0; ks < 2; ++ks)
      aq[mf][ks] = ld16(qkvr + ((size_t)(qmt + mf) * 288 + h * 8 + ks * 4 + quad) * 128
                        + l15 * 8);

  u32x4 rk[2], rv[2];
  auto load_kv = [&](int kt) {
#pragma unroll
    for (int j = 0; j < 2; ++j) {
      int u = w * 2 + j;
      rk[j] = *(const u32x4*)(qkvr + ((size_t)(kb16 + kt * 4 + (u >> 1)) * 288
                                      + 96 + h * 8 + (u & 1) * 4) * 128 + lane * 8);
      rv[j] = *(const u32x4*)(vbase + ((size_t)(u >> 1) * 128 + kt * 8
                                       + (u & 1) * 4) * 128 + lane * 8);
    }
  };
  auto store_kv = [&]() {
#pragma unroll
    for (int j = 0; j < 2; ++j) {
      int slot = (w * 2 + j) * 4 + (lane >> 4);
      *(u32x4*)(Ks + slot * CH + l15 * 8) = rk[j];
      *(u32x4*)(Vt + slot * CH + l15 * 8) = rv[j];
    }
  };

  f32x4 O[2][4] = {};
  float lsum[2][4] = {};
  us* myP = Ps[w];

  load_kv(0);
  store_kv();
  __syncthreads();

  for (int kt = 0; kt < 16; ++kt) {
    if (kt + 1 < 16) load_kv(kt + 1);

    // S = Q K^T
    f32x4 s[2][4] = {};
#pragma unroll
    for (int ks = 0; ks < 2; ++ks)
#pragma unroll
      for (int nf = 0; nf < 4; ++nf) {
        bf16x8 bk = ld16(Ks + (nf * 8 + ks * 4 + quad) * CH + l15 * 8);
        s[0][nf] = MFMA16(aq[0][ks], bk, s[0][nf]);
        s[1][nf] = MFMA16(aq[1][ks], bk, s[1][nf]);
      }

    // static-max softmax; per-lane partial l sums
#pragma unroll
    for (int mf = 0; mf < 2; ++mf)
#pragma unroll
      for (int r = 0; r < 4; ++r) {
        float p0 = __builtin_amdgcn_exp2f(s[mf][0][r] * c1);
        float p1 = __builtin_amdgcn_exp2f(s[mf][1][r] * c1);
        float p2 = __builtin_amdgcn_exp2f(s[mf][2][r] * c1);
        float p3 = __builtin_amdgcn_exp2f(s[mf][3][r] * c1);
        lsum[mf][r] += (p0 + p1) + (p2 + p3);
        int rowq = (mf * 16 + quad * 4 + r) * 72 + l15;
        myP[rowq]      = f2bf(p0);
        myP[rowq + 16] = f2bf(p1);
        myP[rowq + 32] = f2bf(p2);
        myP[rowq + 48] = f2bf(p3);
      }

    // O += P V
#pragma unroll
    for (int k2 = 0; k2 < 2; ++k2) {
      bf16x8 pa0 = ld16(myP + l15 * 72 + k2 * 32 + quad * 8);
      bf16x8 pa1 = ld16(myP + (16 + l15) * 72 + k2 * 32 + quad * 8);
#pragma unroll
      for (int df = 0; df < 4; ++df) {
        bf16x8 bv = ld16(Vt + (df * 8 + k2 * 4 + quad) * CH + l15 * 8);
        O[0][df] = MFMA16(pa0, bv, O[0][df]);
        O[1][df] = MFMA16(pa1, bv, O[1][df]);
      }
    }

    __syncthreads();
    if (kt + 1 < 16) {
      store_kv();
      __syncthreads();
    }
  }

  // epilogue: l-reduction, scale, store ctx TILED (96 k-chunks)
  const int omt = (hf * 4096 + b * 1024 + r0) >> 4;
#pragma unroll
  for (int mf = 0; mf < 2; ++mf)
#pragma unroll
    for (int r = 0; r < 4; ++r) {
      float l = lsum[mf][r];
#pragma unroll
      for (int o = 1; o < 16; o <<= 1) l += __shfl_xor(l, o);
      float inv = 1.0f / l;
      size_t cb = ((size_t)(omt + mf) * 96 + h * 8 + (l15 >> 3)) * 128
                + (quad * 4 + r) * 8 + (l15 & 7);
#pragma unroll
      for (int df = 0; df < 4; ++df)
        ctx[cb + df * 256] = f2bf(O[mf][df][r] * inv);
    }
}

// ------------------------------------------------------------------ launch --
extern "C" void kernel_launch(void* const* d_in, const int* in_sizes, int n_in,
                              void* d_out, int out_size, void* d_ws, size_t ws_size,
                              hipStream_t stream) {
  (void)in_sizes; (void)n_in; (void)out_size; (void)ws_size;
  const float* before = (const float*)d_in[0];
  const float* after  = (const float*)d_in[1];
  const float* wqkv   = (const float*)d_in[2];
  const float* lng    = (const float*)d_in[3];
  const float* lnb    = (const float*)d_in[4];
  const float* wproj  = (const float*)d_in[5];
  const float* bproj  = (const float*)d_in[6];
  float* out = (float*)d_out;
  us* ws  = (us*)d_ws;
  us* xbt = ws;
  us* vtg = ws;                      // reuses xbt after gemm_qkv
  us* wqt = ws + 6291456;
  us* wpt = ws + 8060928;
  us* qkvr = ws + 8650752;
  us* ctx  = ws + 27525120;

  k_convert<<<4224, 256, 0, stream>>>(before, after, wqkv, wproj, ws);
  k_gemm<128, 0><<<dim3(64, 18), 256, 0, stream>>>(
      xbt, wqt, (void*)qkvr, nullptr, nullptr, lng, lnb);
  k_vt<<<dim3(96, 16), 256, 0, stream>>>(qkvr, vtg);
  k_attn<<<dim3(96, 8), 256, 0, stream>>>(qkvr, vtg, ctx);
  k_gemm<64, 1><<<dim3(128, 6), 256, 0, stream>>>(
      ctx, wpt, (void*)out, qkvr, bproj, nullptr, nullptr);
}

// Round 8
// 194.318 us; speedup vs baseline: 1.5748x; 1.0932x over previous
//
#include <hip/hip_runtime.h>

// ---------------------------------------------------------------------------
// Fused: qkv-proj + head-LN -> cross-attention (x2) -> proj.
// B=4, N=1024, C=768, H=12, HD=64.  MFMA bf16 16x16x32, f32 accum.
//
// Round-8:
//  * fragment-tiled bf16 layout (1KB coalesced wave loads) everywhere.
//  * GEMM/attn: reg->LDS single-buffer pipeline with RAW lgkm-only barriers
//    (no vmcnt(0) drain; compiler emits dataflow vmcnt in store_regs, ~250+
//    cycles after issue).  Works now because loads no longer shatter (r5/r6
//    fix) and LDS stays single-buffered (r4's occupancy mistake avoided).
//  * k_vt DELETED: V-transpose fused into gemm_qkv epilogue (C-layout accs
//    have 4 consecutive keys per lane -> packed 8B transposed stores).
//    qkvr holds q,k only (192 chunks); vtg takes the freed space.
//  * XCD-aware grids: gemm x=m-tile (same-A co-XCD); attn x=head-instance
//    (per-head K/V L2-hot, 3MB/XCD).
//
// ws layout (ushort elements):
//   xbt  @ 0        : tiled [8192 x 768]  (rows 0..4095 before, rest after)
//   wqt  @ 6291456  : tiled [2304 x 768]
//   wpt  @ 8060928  : tiled [768 x 768]
//   qkvr @ 8650752  : tiled [8192 x 1536] post-LN q,k (192 k-chunks)
//   vtg  @ 21233664 : 96 heads x tiled [64 d x 1024 key]
//   ctx  @ 27525120 : tiled [8192 x 768]
// ---------------------------------------------------------------------------

typedef __bf16 bf16x8 __attribute__((ext_vector_type(8)));
typedef float  f32x4  __attribute__((ext_vector_type(4)));
typedef unsigned int u32x4 __attribute__((ext_vector_type(4)));
typedef unsigned short us;

#define MFMA16(a, b, c) __builtin_amdgcn_mfma_f32_16x16x32_bf16(a, b, c, 0, 0, 0)

__device__ __forceinline__ us f2bf(float f) {
  unsigned int u = __builtin_bit_cast(unsigned int, f);
  u += 0x7FFFu + ((u >> 16) & 1u);   // RNE
  return (us)(u >> 16);
}
__device__ __forceinline__ float bf2f(us h) {
  unsigned int u = ((unsigned int)h) << 16;
  return __builtin_bit_cast(float, u);
}
__device__ __forceinline__ bf16x8 ld16(const us* p) {
  return __builtin_bit_cast(bf16x8, *(const u32x4*)p);
}
// Raw barrier: orders LDS only; in-flight global loads stay in flight.
__device__ __forceinline__ void barrier_lds() {
  asm volatile("s_waitcnt lgkmcnt(0)\n\ts_barrier" ::: "memory");
}

// LDS chunk stride: 128 elems payload padded to 136 (272B; 68 words ≡ 4
// mod 32 -> quad-adjacent chunks hit shifted banks).
#define CH 136

// ---------------------------------------------------------------- convert --
// f32 row-major -> bf16 fragment-tiled.  One 16B tiled piece per thread.
__global__ __launch_bounds__(256) void k_convert(
    const float* __restrict__ before, const float* __restrict__ after,
    const float* __restrict__ wqkv, const float* __restrict__ wproj,
    us* __restrict__ ws) {
  int t = blockIdx.x * 256 + threadIdx.x;
  us* dst; int u;
  if (t < 786432)       { u = t;           dst = ws; }
  else if (t < 1007616) { u = t - 786432;  dst = ws + 6291456; }
  else                  { u = t - 1007616; dst = ws + 8060928; }
  int l15 = u & 15, c2 = u >> 4;
  int kc = c2 % 96, mt = c2 / 96;
  int row = mt * 16 + l15;
  const float* srow;
  if (t < 786432)       srow = row < 4096 ? before + (size_t)row * 768
                                          : after + (size_t)(row - 4096) * 768;
  else if (t < 1007616) srow = wqkv + (size_t)row * 768;
  else                  srow = wproj + (size_t)row * 768;
  const float4* s4 = (const float4*)(srow + kc * 8);
  float4 a = s4[0], b = s4[1];
  union { u32x4 v; us s[8]; } o;
  o.s[0] = f2bf(a.x); o.s[1] = f2bf(a.y); o.s[2] = f2bf(a.z); o.s[3] = f2bf(a.w);
  o.s[4] = f2bf(b.x); o.s[5] = f2bf(b.y); o.s[6] = f2bf(b.z); o.s[7] = f2bf(b.w);
  *(u32x4*)(dst + (size_t)c2 * 128 + l15 * 8) = o.v;
}

// -------------------------------------------------------------- gemm main --
// NT GEMM main loop on tiled operands, block tile MT x 128, 4 waves (2x2),
// K=768 (12 x BK=64).  Single-buffer LDS, raw lgkm barriers, reg prefetch.
template <int MT>
__device__ __forceinline__ void gemm_mainloop(
    const us* __restrict__ A, const us* __restrict__ B,
    int m0, int n0, us* As, us* Bs, f32x4 (&acc)[MT / 32][4]) {
  constexpr int AJ = MT / 32;
  constexpr int NITER = 12;
  const int tid = threadIdx.x, lane = tid & 63, w = tid >> 6;
  const int quad = lane >> 4, l15 = lane & 15;
  const int wm = (w >> 1) * (MT / 2), wn = (w & 1) * 64;
  u32x4 ra[AJ], rb[4];

  auto load_regs = [&](int k0) {
#pragma unroll
    for (int j = 0; j < AJ; ++j) {
      int u = w * AJ + j;
      ra[j] = *(const u32x4*)(A + ((size_t)((m0 >> 4) + (u >> 1)) * 96
                                   + (k0 >> 3) + (u & 1) * 4) * 128 + lane * 8);
    }
#pragma unroll
    for (int j = 0; j < 4; ++j) {
      int u = w * 4 + j;
      rb[j] = *(const u32x4*)(B + ((size_t)((n0 >> 4) + (u >> 1)) * 96
                                   + (k0 >> 3) + (u & 1) * 4) * 128 + lane * 8);
    }
  };
  auto store_regs = [&]() {
#pragma unroll
    for (int j = 0; j < AJ; ++j) {
      int slot = (w * AJ + j) * 4 + quad;
      *(u32x4*)(As + slot * CH + l15 * 8) = ra[j];
    }
#pragma unroll
    for (int j = 0; j < 4; ++j) {
      int slot = (w * 4 + j) * 4 + quad;
      *(u32x4*)(Bs + slot * CH + l15 * 8) = rb[j];
    }
  };

  load_regs(0);
  store_regs();
  barrier_lds();

#pragma unroll
  for (int it = 0; it < NITER; ++it) {
    if (it + 1 < NITER) load_regs((it + 1) * 64);
#pragma unroll
    for (int ks = 0; ks < 2; ++ks) {
      bf16x8 af[AJ], bfr[4];
#pragma unroll
      for (int mf = 0; mf < AJ; ++mf)
        af[mf] = ld16(As + (((wm >> 4) + mf) * 8 + ks * 4 + quad) * CH + l15 * 8);
#pragma unroll
      for (int nf = 0; nf < 4; ++nf)
        bfr[nf] = ld16(Bs + (((wn >> 4) + nf) * 8 + ks * 4 + quad) * CH + l15 * 8);
#pragma unroll
      for (int mf = 0; mf < AJ; ++mf)
#pragma unroll
        for (int nf = 0; nf < 4; ++nf)
          acc[mf][nf] = MFMA16(af[mf], bfr[nf], acc[mf][nf]);
    }
    barrier_lds();                       // all waves done reading LDS
    if (it + 1 < NITER) {
      store_regs();                      // dataflow vmcnt waits land here
      barrier_lds();
    }
  }
}

// --------------------------------------------------------------- gemm qkv --
// grid (64 m-tiles, 18 n-tiles); XCD = m%8 (same-A co-XCD).  Per-head LN
// epilogue.  cols < 1536 -> tiled qkvr (192 chunks); cols >= 1536 (v) ->
// TRANSPOSED tiled vtg (fused k_vt).
__global__ __launch_bounds__(256) void k_gemm_qkv(
    const us* __restrict__ A, const us* __restrict__ B, us* __restrict__ Cqk,
    us* __restrict__ Vg, const float* __restrict__ g, const float* __restrict__ bb) {
  __shared__ us As[64 * CH];
  __shared__ us Bs[64 * CH];
  const int lane = threadIdx.x & 63, w = threadIdx.x >> 6;
  const int quad = lane >> 4, l15 = lane & 15;
  const int m0 = blockIdx.x * 128, n0 = blockIdx.y * 128;
  const int wm = (w >> 1) * 64, wn = (w & 1) * 64;
  f32x4 acc[4][4] = {};
  gemm_mainloop<128>(A, B, m0, n0, As, Bs, acc);

  float gl[4], bl[4];
#pragma unroll
  for (int nf = 0; nf < 4; ++nf) { gl[nf] = g[nf * 16 + l15]; bl[nf] = bb[nf * 16 + l15]; }

  if ((n0 + wn) < 1536) {
    // q/k -> tiled qkvr (192 k-chunks)
#pragma unroll
    for (int mf = 0; mf < 4; ++mf)
#pragma unroll
      for (int r = 0; r < 4; ++r) {
        float s1 = acc[mf][0][r] + acc[mf][1][r] + acc[mf][2][r] + acc[mf][3][r];
        float s2 = acc[mf][0][r] * acc[mf][0][r] + acc[mf][1][r] * acc[mf][1][r]
                 + acc[mf][2][r] * acc[mf][2][r] + acc[mf][3][r] * acc[mf][3][r];
#pragma unroll
        for (int o = 1; o < 16; o <<= 1) { s1 += __shfl_xor(s1, o); s2 += __shfl_xor(s2, o); }
        float mu = s1 * (1.0f / 64.0f);
        float var = s2 * (1.0f / 64.0f) - mu * mu;
        float sc = rsqrtf(var + 1e-5f);
        size_t cb = ((size_t)(((m0 + wm) >> 4) + mf) * 192 + ((n0 + wn) >> 3)
                     + (l15 >> 3)) * 128 + (quad * 4 + r) * 8 + (l15 & 7);
#pragma unroll
        for (int nf = 0; nf < 4; ++nf)
          Cqk[cb + nf * 256] = f2bf((acc[mf][nf][r] - mu) * sc * gl[nf] + bl[nf]);
      }
  } else {
    // v -> transposed tiled vtg[hi][d][key]
    const int h = ((n0 + wn) - 1536) >> 6;
#pragma unroll
    for (int mf = 0; mf < 4; ++mf) {
      int mrow = m0 + wm + mf * 16;        // 16-aligned
      int s = mrow >> 12, b2 = (mrow >> 10) & 3;
      int K0 = mrow & 1023;
      us* vb = Vg + (size_t)(s * 48 + b2 * 12 + h) * 65536;
      float vv[4][4];
#pragma unroll
      for (int r = 0; r < 4; ++r) {
        float s1 = acc[mf][0][r] + acc[mf][1][r] + acc[mf][2][r] + acc[mf][3][r];
        float s2 = acc[mf][0][r] * acc[mf][0][r] + acc[mf][1][r] * acc[mf][1][r]
                 + acc[mf][2][r] * acc[mf][2][r] + acc[mf][3][r] * acc[mf][3][r];
#pragma unroll
        for (int o = 1; o < 16; o <<= 1) { s1 += __shfl_xor(s1, o); s2 += __shfl_xor(s2, o); }
        float mu = s1 * (1.0f / 64.0f);
        float var = s2 * (1.0f / 64.0f) - mu * mu;
        float sc = rsqrtf(var + 1e-5f);
#pragma unroll
        for (int nf = 0; nf < 4; ++nf)
          vv[nf][r] = (acc[mf][nf][r] - mu) * sc * gl[nf] + bl[nf];
      }
#pragma unroll
      for (int nf = 0; nf < 4; ++nf) {
        ushort4 o4;
        o4.x = f2bf(vv[nf][0]); o4.y = f2bf(vv[nf][1]);
        o4.z = f2bf(vv[nf][2]); o4.w = f2bf(vv[nf][3]);
        *(ushort4*)(vb + ((size_t)nf * 128 + (K0 >> 3) + (quad >> 1)) * 128
                    + l15 * 8 + (quad & 1) * 4) = o4;
      }
    }
  }
}

// -------------------------------------------------------------- gemm proj --
// grid (128 m-tiles, 6 n-tiles).  f32 row-major out + bias + untransposed-q
// residual (from tiled qkvr, 192 chunks).
__global__ __launch_bounds__(256) void k_gemm_proj(
    const us* __restrict__ A, const us* __restrict__ B, float* __restrict__ C,
    const us* __restrict__ qkvr, const float* __restrict__ bias) {
  __shared__ us As[32 * CH];
  __shared__ us Bs[64 * CH];
  const int lane = threadIdx.x & 63, w = threadIdx.x >> 6;
  const int quad = lane >> 4, l15 = lane & 15;
  const int m0 = blockIdx.x * 64, n0 = blockIdx.y * 128;
  const int wm = (w >> 1) * 32, wn = (w & 1) * 64;
  f32x4 acc[2][4] = {};
  gemm_mainloop<64>(A, B, m0, n0, As, Bs, acc);

  const int cg = (n0 + wn) >> 6;          // wave-uniform column group
  float bl[4];
#pragma unroll
  for (int nf = 0; nf < 4; ++nf) bl[nf] = bias[n0 + wn + nf * 16 + l15];
#pragma unroll
  for (int mf = 0; mf < 2; ++mf)
#pragma unroll
    for (int r = 0; r < 4; ++r) {
      int row = m0 + wm + mf * 16 + quad * 4 + r;
      int hf = row >> 12;                 // 0 -> context_b (q=after), 1 -> context_a
      int m4 = row & 4095;
      int b = m4 >> 10, i = m4 & 1023;
      int j = i * 12 + cg;                // f>>6 where f = i*768+col
      int h = j >> 10, n = j & 1023;      // d = nf*16 + l15
      int qrow = ((hf ^ 1) << 12) + (b << 10) + n;
      size_t rb2 = ((size_t)(qrow >> 4) * 192 + h * 8 + (l15 >> 3)) * 128
                 + (qrow & 15) * 8 + (l15 & 7);
      size_t base = (size_t)row * 768 + n0 + wn + l15;
#pragma unroll
      for (int nf = 0; nf < 4; ++nf)
        C[base + nf * 16] = acc[mf][nf][r] + bl[nf] + bf2f(qkvr[rb2 + nf * 256]);
    }
}

// -------------------------------------------------------------- attention --
// grid (96 hi, 8 qt) -> XCD = hi%8 (per-head K/V L2-hot).  K/V staged via
// LDS with reg prefetch + raw lgkm barriers.  Static-max softmax, deferred
// l-reduction.
__global__ __launch_bounds__(256) void k_attn(const us* __restrict__ qkvr,
                                              const us* __restrict__ vtg,
                                              us* __restrict__ ctx) {
  __shared__ us Ks[32 * CH];
  __shared__ us Vt[32 * CH];
  __shared__ us Ps[4][32 * 72];
  const int tid = threadIdx.x, lane = tid & 63, w = tid >> 6;
  const int quad = lane >> 4, l15 = lane & 15;
  const int hi = blockIdx.x, qt = blockIdx.y;
  const int hf = hi / 48, bh = hi - hf * 48;
  const int b = bh / 12, h = bh - (bh / 12) * 12;
  const int ihq = hf ^ 1, ihk = hf;
  const int r0 = qt * 128 + w * 32;
  const int qmt = (ihq * 4096 + b * 1024 + r0) >> 4;
  const int kb16 = (ihk * 4096 + b * 1024) >> 4;
  const us* vbase = vtg + (size_t)(ihk * 48 + b * 12 + h) * 65536;
  const float c1 = 0.125f * 1.44269504088896340736f;  // scale * log2(e)

  // Q fragments resident (A-layout), direct from tiled global
  bf16x8 aq[2][2];
#pragma unroll
  for (int mf = 0; mf < 2; ++mf)
#pragma unroll
    for (int ks = 0; ks < 2; ++ks)
      aq[mf][ks] = ld16(qkvr + ((size_t)(qmt + mf) * 192 + h * 8 + ks * 4 + quad) * 128
                        + l15 * 8);

  u32x4 rk[2], rv[2];
  auto load_kv = [&](int kt) {
#pragma unroll
    for (int j = 0; j < 2; ++j) {
      int u = w * 2 + j;
      rk[j] = *(const u32x4*)(qkvr + ((size_t)(kb16 + kt * 4 + (u >> 1)) * 192
                                      + 96 + h * 8 + (u & 1) * 4) * 128 + lane * 8);
      rv[j] = *(const u32x4*)(vbase + ((size_t)(u >> 1) * 128 + kt * 8
                                       + (u & 1) * 4) * 128 + lane * 8);
    }
  };
  auto store_kv = [&]() {
#pragma unroll
    for (int j = 0; j < 2; ++j) {
      int slot = (w * 2 + j) * 4 + quad;
      *(u32x4*)(Ks + slot * CH + l15 * 8) = rk[j];
      *(u32x4*)(Vt + slot * CH + l15 * 8) = rv[j];
    }
  };

  f32x4 O[2][4] = {};
  float lsum[2][4] = {};
  us* myP = Ps[w];

  load_kv(0);
  store_kv();
  barrier_lds();

  for (int kt = 0; kt < 16; ++kt) {
    if (kt + 1 < 16) load_kv(kt + 1);

    // S = Q K^T
    f32x4 s[2][4] = {};
#pragma unroll
    for (int ks = 0; ks < 2; ++ks)
#pragma unroll
      for (int nf = 0; nf < 4; ++nf) {
        bf16x8 bk = ld16(Ks + (nf * 8 + ks * 4 + quad) * CH + l15 * 8);
        s[0][nf] = MFMA16(aq[0][ks], bk, s[0][nf]);
        s[1][nf] = MFMA16(aq[1][ks], bk, s[1][nf]);
      }

    // static-max softmax; per-lane partial l sums
#pragma unroll
    for (int mf = 0; mf < 2; ++mf)
#pragma unroll
      for (int r = 0; r < 4; ++r) {
        float p0 = __builtin_amdgcn_exp2f(s[mf][0][r] * c1);
        float p1 = __builtin_amdgcn_exp2f(s[mf][1][r] * c1);
        float p2 = __builtin_amdgcn_exp2f(s[mf][2][r] * c1);
        float p3 = __builtin_amdgcn_exp2f(s[mf][3][r] * c1);
        lsum[mf][r] += (p0 + p1) + (p2 + p3);
        int rowq = (mf * 16 + quad * 4 + r) * 72 + l15;
        myP[rowq]      = f2bf(p0);
        myP[rowq + 16] = f2bf(p1);
        myP[rowq + 32] = f2bf(p2);
        myP[rowq + 48] = f2bf(p3);
      }

    // O += P V   (per-wave LDS round-trip)
#pragma unroll
    for (int k2 = 0; k2 < 2; ++k2) {
      bf16x8 pa0 = ld16(myP + l15 * 72 + k2 * 32 + quad * 8);
      bf16x8 pa1 = ld16(myP + (16 + l15) * 72 + k2 * 32 + quad * 8);
#pragma unroll
      for (int df = 0; df < 4; ++df) {
        bf16x8 bv = ld16(Vt + (df * 8 + k2 * 4 + quad) * CH + l15 * 8);
        O[0][df] = MFMA16(pa0, bv, O[0][df]);
        O[1][df] = MFMA16(pa1, bv, O[1][df]);
      }
    }

    barrier_lds();
    if (kt + 1 < 16) {
      store_kv();
      barrier_lds();
    }
  }

  // epilogue: l-reduction, scale, store ctx TILED (96 k-chunks)
  const int omt = (hf * 4096 + b * 1024 + r0) >> 4;
#pragma unroll
  for (int mf = 0; mf < 2; ++mf)
#pragma unroll
    for (int r = 0; r < 4; ++r) {
      float l = lsum[mf][r];
#pragma unroll
      for (int o = 1; o < 16; o <<= 1) l += __shfl_xor(l, o);
      float inv = 1.0f / l;
      size_t cb = ((size_t)(omt + mf) * 96 + h * 8 + (l15 >> 3)) * 128
                + (quad * 4 + r) * 8 + (l15 & 7);
#pragma unroll
      for (int df = 0; df < 4; ++df)
        ctx[cb + df * 256] = f2bf(O[mf][df][r] * inv);
    }
}

// ------------------------------------------------------------------ launch --
extern "C" void kernel_launch(void* const* d_in, const int* in_sizes, int n_in,
                              void* d_out, int out_size, void* d_ws, size_t ws_size,
                              hipStream_t stream) {
  (void)in_sizes; (void)n_in; (void)out_size; (void)ws_size;
  const float* before = (const float*)d_in[0];
  const float* after  = (const float*)d_in[1];
  const float* wqkv   = (const float*)d_in[2];
  const float* lng    = (const float*)d_in[3];
  const float* lnb    = (const float*)d_in[4];
  const float* wproj  = (const float*)d_in[5];
  const float* bproj  = (const float*)d_in[6];
  float* out = (float*)d_out;
  us* ws  = (us*)d_ws;
  us* xbt  = ws;
  us* wqt  = ws + 6291456;
  us* wpt  = ws + 8060928;
  us* qkvr = ws + 8650752;
  us* vtg  = ws + 21233664;
  us* ctx  = ws + 27525120;

  k_convert<<<4224, 256, 0, stream>>>(before, after, wqkv, wproj, ws);
  k_gemm_qkv<<<dim3(64, 18), 256, 0, stream>>>(xbt, wqt, qkvr, vtg, lng, lnb);
  k_attn<<<dim3(96, 8), 256, 0, stream>>>(qkvr, vtg, ctx);
  k_gemm_proj<<<dim3(128, 6), 256, 0, stream>>>(ctx, wpt, out, qkvr, bproj);
}